// Round 12
// baseline (3789.595 us; speedup 1.0000x reference)
//
#include <hip/hip_runtime.h>
#include <hip/hip_fp16.h>
#include <cstddef>

#define NMOD 64
#define HID 512
#define TSTEPS 1024
#define G4 2048           // gate rows per module

// ws layout
#define WOFF_PERMOD 0            // 64 f32
#define WOFF_HX     16384        // 2*64*256 u64 seq-tagged h pairs = 256 KB
#define WOFF_W16    524288       // fragment-ordered f16 weights, 128 MB
#define W16_BYTES   ((size_t)NMOD * G4 * HID * 2)
#define WS_NEED     (WOFF_W16 + W16_BYTES)

typedef _Float16 half8_t __attribute__((ext_vector_type(8)));
typedef float    f32x4_t __attribute__((ext_vector_type(4)));

__device__ __forceinline__ float fsig(float x)  { return 1.0f / (1.0f + __expf(-x)); }
__device__ __forceinline__ float ftanh_(float x){ return 1.0f - 2.0f / (__expf(2.0f * x) + 1.0f); }

__device__ __forceinline__ half8_t h8(uint4 u) { return __builtin_bit_cast(half8_t, u); }

#define MFMA_F16(a, b, c) __builtin_amdgcn_mfma_f32_16x16x32_f16((a), (b), (c), 0, 0, 0)
#define ALOAD(p) __hip_atomic_load((p), __ATOMIC_RELAXED, __HIP_MEMORY_SCOPE_AGENT)

// ---------------- f32 -> f16 fragment-ordered conversion (proven in R11) ----
__global__ __launch_bounds__(256) void conv_frag_kernel(const float* __restrict__ src,
                                                        unsigned* __restrict__ dst) {
    const unsigned t_lin = blockIdx.x * 256 + threadIdx.x;
    const unsigned chunk = t_lin >> 6, u = t_lin & 63;
    const unsigned l = ((u & 3) << 4) | (u >> 2);
    const unsigned t = (chunk << 6) | l;

    const int ll = t & 63;
    const int j  = (t >> 6) & 15;
    const int mt = (t >> 10) & 3;
    const int w  = (t >> 12) & 7;
    const int b  = (t >> 15) & 3;
    const int m  = (int)(t >> 17);
    const int kc = (4 * b + j) & 15;
    const int g  = ll >> 4, r16 = ll & 15;
    const int lr = w * 64 + mt * 16 + r16;
    const int gr = (lr >> 7) * 512 + b * 128 + (lr & 127);

    const float* sp = src + ((size_t)m * G4 + gr) * HID + kc * 32 + g * 8;
    const float4 a = *reinterpret_cast<const float4*>(sp);
    const float4 c = *reinterpret_cast<const float4*>(sp + 4);
    __half2 h0 = __floats2half2_rn(a.x, a.y);
    __half2 h1 = __floats2half2_rn(a.z, a.w);
    __half2 h2 = __floats2half2_rn(c.x, c.y);
    __half2 h3 = __floats2half2_rn(c.z, c.w);
    uint4 o;
    o.x = *reinterpret_cast<unsigned*>(&h0);
    o.y = *reinterpret_cast<unsigned*>(&h1);
    o.z = *reinterpret_cast<unsigned*>(&h2);
    o.w = *reinterpret_cast<unsigned*>(&h3);
    *reinterpret_cast<uint4*>(dst + (size_t)t * 4) = o;
}

// ---------------- MFMA LSTM, per-wave redundant polling, 1 barrier/step -----
// 4 blocks/module, 512 thr (8 waves), 1 block/CU. Each wave polls ALL 256
// h-words itself (4/lane: local word + 3 remotes) into its PRIVATE LDS stage
// -> no cross-wave h handoff, no h barriers. Local-region MFMAs (4 chunks)
// overlap the remote-poll RTT. Only the gates barrier remains (1/step).
// Seq-tag u64 + parity dbuf protocol unchanged (skew<=1 proof holds).
__global__
__attribute__((amdgpu_flat_work_group_size(512, 512), amdgpu_waves_per_eu(2, 2)))
void lstm_mfma_kernel(
    const float* __restrict__ recent,
    const float* __restrict__ history,
    const float* __restrict__ W_ih,
    const float* __restrict__ b_ih,
    const float* __restrict__ b_hh,
    const float* __restrict__ lin_W,
    const float* __restrict__ lin_b,
    const unsigned* __restrict__ wf,    // fragment-ordered f16 weights
    unsigned long long* hx,             // [2][64][256] seq-tagged pairs, zeroed
    float* __restrict__ per_mod)        // [64]
{
    const int bid = blockIdx.x;
    const int m = (bid & 7) * 8 + (bid >> 5);
    const int b = (bid >> 3) & 3;
    const int tid = threadIdx.x;
    const int w   = tid >> 6;   // wave 0..7
    const int l   = tid & 63;
    const int g   = l >> 4;     // 16-lane group 0..3
    const int c16 = l & 15;

    __shared__ uint4 w_lds[8][4][4][64];   // 128 KB [wave][mt][j2][lane]
    __shared__ unsigned h_stage[8][256];   // 8 KB per-wave h payload stage
    __shared__ float gates_sh[512];
    __shared__ float hist_sh[TSTEPS];
    __shared__ float red_sh[8];

    for (int i = tid; i < TSTEPS; i += 512)
        hist_sh[i] = history[(size_t)m * TSTEPS + i];

    // ---- load fragment weights: 12 K-chunks/tile in regs (AGPR-backed,
    // MFMA reads AGPR A-operands natively), 4 in LDS ----
    const uint4* fb = (const uint4*)wf + (size_t)((m * 4 + b) * 8 + w) * 4096;
    uint4 wr[4][12];
    #pragma unroll
    for (int mt = 0; mt < 4; ++mt)
        #pragma unroll
        for (int j = 0; j < 12; ++j)
            wr[mt][j] = fb[(mt * 16 + j) * 64 + l];
    #pragma unroll
    for (int mt = 0; mt < 4; ++mt)
        #pragma unroll
        for (int j2 = 0; j2 < 4; ++j2)
            w_lds[w][mt][j2][l] = fb[(mt * 16 + 12 + j2) * 64 + l];

    // gate-writeback constants: lanes c16<4 own tile mt=c16, rows g*4+e
    float wib4[4], bias4[4];
    if (c16 < 4) {
        #pragma unroll
        for (int e = 0; e < 4; ++e) {
            const int lr = w * 64 + c16 * 16 + g * 4 + e;
            const int gr = (lr >> 7) * 512 + b * 128 + (lr & 127);
            wib4[e]  = W_ih[(size_t)m * G4 + gr];
            bias4[e] = b_ih[(size_t)m * G4 + gr] + b_hh[(size_t)m * G4 + gr];
        }
    }

    // per-lane poll addresses: local word + 3 remote words (covers all 256)
    const int wloc = (b << 6) + l;
    const int wr0  = (((b + 1) & 3) << 6) + l;
    const int wr1  = (((b + 2) & 3) << 6) + l;
    const int wr2  = (((b + 3) & 3) << 6) + l;

    float c0 = 0.0f;   // cell state, lives in tid<128
    __syncthreads();   // hist staged before prologue reads

    // prologue gates(t=0): h(0)=0 -> input+bias only
    if (c16 < 4) {
        const float x0 = hist_sh[0];
        float4 o;
        o.x = x0 * wib4[0] + bias4[0];
        o.y = x0 * wib4[1] + bias4[1];
        o.z = x0 * wib4[2] + bias4[2];
        o.w = x0 * wib4[3] + bias4[3];
        *reinterpret_cast<float4*>(&gates_sh[w * 64 + c16 * 16 + g * 4]) = o;
    }

    for (int t = 0; t < TSTEPS - 1; ++t) {
        __syncthreads();   // gates(t) ready (the ONLY barrier per step)
        const unsigned seq = (unsigned)(t + 1);
        const size_t pbase = (size_t)(seq & 1) * (NMOD * 256) + (size_t)m * 256;

        if (tid < 128) {
            // cell update for h elem tid of this block's 128-segment
            const float gi = fsig(gates_sh[tid]);
            const float gf = fsig(gates_sh[128 + tid]);
            const float gg = ftanh_(gates_sh[256 + tid]);
            const float go = fsig(gates_sh[384 + tid]);
            c0 = gf * c0 + gi * gg;
            const float hv = go * ftanh_(c0);
            const float ho = __shfl_xor(hv, 1, 64);
            if ((tid & 1) == 0) {
                __half2 hh = __floats2half2_rn(hv, ho);
                const unsigned pay = *reinterpret_cast<unsigned*>(&hh);
                __hip_atomic_store(&hx[pbase + b * 64 + (tid >> 1)],
                                   ((unsigned long long)seq << 32) | pay,
                                   __ATOMIC_RELAXED, __HIP_MEMORY_SCOPE_AGENT);
            }
        }

        // every wave polls its own full copy: local + 3 speculative remotes
        unsigned long long a0 = ALOAD(&hx[pbase + wloc]);
        unsigned long long r0 = ALOAD(&hx[pbase + wr0]);
        unsigned long long r1 = ALOAD(&hx[pbase + wr1]);
        unsigned long long r2 = ALOAD(&hx[pbase + wr2]);
        while ((unsigned)(a0 >> 32) != seq) a0 = ALOAD(&hx[pbase + wloc]);
        h_stage[w][wloc] = (unsigned)a0;   // wave-private: no barrier needed

        // ---- local K-chunks (kc=4b..4b+3) overlap remote RTT ----
        f32x4_t acc0 = {0.f, 0.f, 0.f, 0.f};
        f32x4_t acc1 = {0.f, 0.f, 0.f, 0.f};
        f32x4_t acc2 = {0.f, 0.f, 0.f, 0.f};
        f32x4_t acc3 = {0.f, 0.f, 0.f, 0.f};
        __builtin_amdgcn_s_setprio(1);
        #pragma unroll
        for (int j = 0; j < 4; ++j) {
            const int kc = 4 * b + j;
            const half8_t hv8 = h8(*(const uint4*)&h_stage[w][kc * 16 + g * 4]);
            acc0 = MFMA_F16(h8(wr[0][j]), hv8, acc0);
            acc1 = MFMA_F16(h8(wr[1][j]), hv8, acc1);
            acc2 = MFMA_F16(h8(wr[2][j]), hv8, acc2);
            acc3 = MFMA_F16(h8(wr[3][j]), hv8, acc3);
        }
        __builtin_amdgcn_s_setprio(0);

        // finish remote polls, stage
        while ((unsigned)(r0 >> 32) != seq || (unsigned)(r1 >> 32) != seq ||
               (unsigned)(r2 >> 32) != seq) {
            if ((unsigned)(r0 >> 32) != seq) r0 = ALOAD(&hx[pbase + wr0]);
            if ((unsigned)(r1 >> 32) != seq) r1 = ALOAD(&hx[pbase + wr1]);
            if ((unsigned)(r2 >> 32) != seq) r2 = ALOAD(&hx[pbase + wr2]);
        }
        h_stage[w][wr0] = (unsigned)r0;
        h_stage[w][wr1] = (unsigned)r1;
        h_stage[w][wr2] = (unsigned)r2;

        // ---- remote K-chunks: j=4..11 regs, j2=0..3 LDS ----
        __builtin_amdgcn_s_setprio(1);
        #pragma unroll
        for (int j = 4; j < 12; ++j) {
            const int kc = (4 * b + j) & 15;
            const half8_t hv8 = h8(*(const uint4*)&h_stage[w][kc * 16 + g * 4]);
            acc0 = MFMA_F16(h8(wr[0][j]), hv8, acc0);
            acc1 = MFMA_F16(h8(wr[1][j]), hv8, acc1);
            acc2 = MFMA_F16(h8(wr[2][j]), hv8, acc2);
            acc3 = MFMA_F16(h8(wr[3][j]), hv8, acc3);
        }
        #pragma unroll
        for (int j2 = 0; j2 < 4; ++j2) {
            const int kc = (4 * b + 12 + j2) & 15;
            const half8_t hv8 = h8(*(const uint4*)&h_stage[w][kc * 16 + g * 4]);
            acc0 = MFMA_F16(h8(w_lds[w][0][j2][l]), hv8, acc0);
            acc1 = MFMA_F16(h8(w_lds[w][1][j2][l]), hv8, acc1);
            acc2 = MFMA_F16(h8(w_lds[w][2][j2][l]), hv8, acc2);
            acc3 = MFMA_F16(h8(w_lds[w][3][j2][l]), hv8, acc3);
        }
        __builtin_amdgcn_s_setprio(0);

        // D cols identical (B bcast): lane (g, c16<4) holds rows g*4+e of
        // tile c16 -> direct float4 gate writeback.
        if (c16 < 4) {
            const f32x4_t a = (c16 == 0) ? acc0 : (c16 == 1) ? acc1
                             : (c16 == 2) ? acc2 : acc3;
            const float x1 = hist_sh[t + 1];
            float4 o;
            o.x = a[0] + x1 * wib4[0] + bias4[0];
            o.y = a[1] + x1 * wib4[1] + bias4[1];
            o.z = a[2] + x1 * wib4[2] + bias4[2];
            o.w = a[3] + x1 * wib4[3] + bias4[3];
            *reinterpret_cast<float4*>(&gates_sh[w * 64 + c16 * 16 + g * 4]) = o;
        }
    }

    // ---- epilogue: final cell update (t = TSTEPS-1) + one exchange ----
    __syncthreads();   // gates(T-1) ready
    {
        const unsigned seq = (unsigned)TSTEPS;
        const size_t pbase = (size_t)(seq & 1) * (NMOD * 256) + (size_t)m * 256;
        if (tid < 128) {
            const float gi = fsig(gates_sh[tid]);
            const float gf = fsig(gates_sh[128 + tid]);
            const float gg = ftanh_(gates_sh[256 + tid]);
            const float go = fsig(gates_sh[384 + tid]);
            c0 = gf * c0 + gi * gg;
            const float hv = go * ftanh_(c0);
            const float ho = __shfl_xor(hv, 1, 64);
            if ((tid & 1) == 0) {
                __half2 hh = __floats2half2_rn(hv, ho);
                const unsigned pay = *reinterpret_cast<unsigned*>(&hh);
                __hip_atomic_store(&hx[pbase + b * 64 + (tid >> 1)],
                                   ((unsigned long long)seq << 32) | pay,
                                   __ATOMIC_RELAXED, __HIP_MEMORY_SCOPE_AGENT);
            }
        }
        if (b == 0) {
            if (tid < 256) {
                unsigned long long pv;
                do {
                    pv = ALOAD(&hx[pbase + tid]);
                } while ((unsigned)(pv >> 32) != seq);
                h_stage[0][tid] = (unsigned)pv;
            }
            __syncthreads();
            // per-module linear from f16 h
            float v = 0.0f;
            if (tid < 256) {
                const __half2 u = *reinterpret_cast<const __half2*>(&h_stage[0][tid]);
                const float* lwp = lin_W + (size_t)m * (HID + 1);
                v = __half2float(u.x) * lwp[2 * tid] + __half2float(u.y) * lwp[2 * tid + 1];
            }
            #pragma unroll
            for (int s2 = 32; s2; s2 >>= 1) v += __shfl_xor(v, s2, 64);
            if ((tid & 63) == 0) red_sh[tid >> 6] = v;
            __syncthreads();
            if (tid == 0) {
                float s = 0.0f;
                #pragma unroll
                for (int wv2 = 0; wv2 < 8; ++wv2) s += red_sh[wv2];
                s += recent[m] * lin_W[(size_t)m * (HID + 1) + HID] + lin_b[m];
                per_mod[m] = s;
            }
        }
    }
}

// ---------------- fallback: round-1 f32 single-block-per-module kernel -------
__global__ __launch_bounds__(1024) void lstm_module_kernel(
    const float* __restrict__ recent,
    const float* __restrict__ history,
    const float* __restrict__ W_ih,
    const float* __restrict__ W_hh,
    const float* __restrict__ b_ih,
    const float* __restrict__ b_hh,
    const float* __restrict__ lin_W,
    const float* __restrict__ lin_b,
    float* __restrict__ per_mod)
{
    const int n = blockIdx.x;
    const int tid = threadIdx.x;

    __shared__ float h_sh[HID];
    __shared__ float gates_sh[G4];
    __shared__ float wib_sh[G4];
    __shared__ float bias_sh[G4];
    __shared__ float hist_sh[TSTEPS];

    for (int i = tid; i < G4; i += 1024) {
        wib_sh[i]  = W_ih[(size_t)n * G4 + i];
        bias_sh[i] = b_ih[(size_t)n * G4 + i] + b_hh[(size_t)n * G4 + i];
    }
    for (int i = tid; i < TSTEPS; i += 1024) hist_sh[i] = history[(size_t)n * TSTEPS + i];
    if (tid < HID) h_sh[tid] = 0.0f;
    float c_reg = 0.0f;
    __syncthreads();

    const int sub = tid & 15;
    const int rid = tid >> 4;
    const float* Wbase = W_hh + (size_t)n * G4 * HID;

    for (int t = 0; t < TSTEPS; ++t) {
        const float x = hist_sh[t];
        float hreg[32];
        #pragma unroll
        for (int j = 0; j < 8; ++j) {
            const float4 hv = *reinterpret_cast<const float4*>(&h_sh[sub * 4 + j * 64]);
            hreg[4 * j + 0] = hv.x; hreg[4 * j + 1] = hv.y;
            hreg[4 * j + 2] = hv.z; hreg[4 * j + 3] = hv.w;
        }
        for (int p = 0; p < 32; ++p) {
            const int r = p * 64 + rid;
            const float* wrp = Wbase + (size_t)r * HID + sub * 4;
            float acc = 0.0f;
            #pragma unroll
            for (int j = 0; j < 8; ++j) {
                const float4 wv = *reinterpret_cast<const float4*>(wrp + j * 64);
                acc += wv.x * hreg[4*j+0] + wv.y * hreg[4*j+1]
                     + wv.z * hreg[4*j+2] + wv.w * hreg[4*j+3];
            }
            acc += __shfl_xor(acc, 1, 64);
            acc += __shfl_xor(acc, 2, 64);
            acc += __shfl_xor(acc, 4, 64);
            acc += __shfl_xor(acc, 8, 64);
            if (sub == 0) gates_sh[r] = acc + x * wib_sh[r] + bias_sh[r];
        }
        __syncthreads();
        if (tid < HID) {
            const float ig = fsig(gates_sh[tid]);
            const float fg = fsig(gates_sh[HID + tid]);
            const float gg = ftanh_(gates_sh[2 * HID + tid]);
            const float og = fsig(gates_sh[3 * HID + tid]);
            c_reg = fg * c_reg + ig * gg;
            h_sh[tid] = og * ftanh_(c_reg);
        }
        __syncthreads();
    }

    if (tid < HID) {
        float v = h_sh[tid] * lin_W[(size_t)n * (HID + 1) + tid];
        #pragma unroll
        for (int m2 = 32; m2; m2 >>= 1) v += __shfl_xor(v, m2, 64);
        if ((tid & 63) == 0) gates_sh[tid >> 6] = v;
    }
    __syncthreads();
    if (tid == 0) {
        float s = 0.0f;
        #pragma unroll
        for (int w = 0; w < HID / 64; ++w) s += gates_sh[w];
        s += recent[n] * lin_W[(size_t)n * (HID + 1) + HID] + lin_b[n];
        per_mod[n] = s;
    }
}

__global__ void finish_kernel(const float* __restrict__ per_mod,
                              const float* __restrict__ final_W,
                              const float* __restrict__ final_b,
                              float* __restrict__ out)
{
    const int l = threadIdx.x;
    float v = per_mod[l] * final_W[l];
    #pragma unroll
    for (int m = 32; m; m >>= 1) v += __shfl_xor(v, m, 64);
    if (l == 0) out[0] = v + final_b[0];
}

extern "C" void kernel_launch(void* const* d_in, const int* in_sizes, int n_in,
                              void* d_out, int out_size, void* d_ws, size_t ws_size,
                              hipStream_t stream) {
    const float* recent  = (const float*)d_in[0];
    const float* history = (const float*)d_in[1];
    const float* W_ih    = (const float*)d_in[2];
    const float* W_hh    = (const float*)d_in[3];
    const float* b_ih    = (const float*)d_in[4];
    const float* b_hh    = (const float*)d_in[5];
    const float* lin_W   = (const float*)d_in[6];
    const float* lin_b   = (const float*)d_in[7];
    const float* final_W = (const float*)d_in[8];
    const float* final_b = (const float*)d_in[9];
    float* out = (float*)d_out;
    float* per_mod = (float*)d_ws;

    if (ws_size >= WS_NEED) {
        unsigned* wfrag = (unsigned*)((char*)d_ws + WOFF_W16);
        unsigned long long* hx = (unsigned long long*)((char*)d_ws + WOFF_HX);

        // zero per_mod + hx each call (ws is not re-poisoned between replays)
        hipMemsetAsync(d_ws, 0, WOFF_W16, stream);

        // 8.39M fragment entries, 1 per thread
        conv_frag_kernel<<<32768, 256, 0, stream>>>(W_hh, wfrag);

        lstm_mfma_kernel<<<NMOD * 4, 512, 0, stream>>>(
            recent, history, W_ih, b_ih, b_hh, lin_W, lin_b,
            wfrag, hx, per_mod);
    } else {
        lstm_module_kernel<<<NMOD, 1024, 0, stream>>>(
            recent, history, W_ih, W_hh, b_ih, b_hh, lin_W, lin_b, per_mod);
    }
    finish_kernel<<<1, 64, 0, stream>>>(per_mod, final_W, final_b, out);
}

// Round 13
// 2361.699 us; speedup vs baseline: 1.6046x; 1.6046x over previous
//
#include <hip/hip_runtime.h>
#include <hip/hip_fp16.h>
#include <cstddef>

#define NMOD 64
#define HID 512
#define TSTEPS 1024
#define G4 2048           // gate rows per module

// ws layout
#define WOFF_PERMOD 0            // 64 f32
#define WOFF_HX     16384        // 2*64*256 u64 seq-tagged h pairs = 256 KB
#define WOFF_W16    524288       // fragment-ordered f16 weights, 128 MB
#define W16_BYTES   ((size_t)NMOD * G4 * HID * 2)
#define WS_NEED     (WOFF_W16 + W16_BYTES)

typedef _Float16 half8_t __attribute__((ext_vector_type(8)));
typedef float    f32x4_t __attribute__((ext_vector_type(4)));

__device__ __forceinline__ float fsig(float x)  { return 1.0f / (1.0f + __expf(-x)); }
__device__ __forceinline__ float ftanh_(float x){ return 1.0f - 2.0f / (__expf(2.0f * x) + 1.0f); }

__device__ __forceinline__ half8_t h8(uint4 u) { return __builtin_bit_cast(half8_t, u); }

#define MFMA_F16(a, b, c) __builtin_amdgcn_mfma_f32_16x16x32_f16((a), (b), (c), 0, 0, 0)
#define ALOAD(p) __hip_atomic_load((p), __ATOMIC_RELAXED, __HIP_MEMORY_SCOPE_AGENT)
#define FLAG_SET(p, v) __hip_atomic_store((p), (v), __ATOMIC_RELEASE, __HIP_MEMORY_SCOPE_WORKGROUP)
#define FLAG_GET(p) __hip_atomic_load((p), __ATOMIC_ACQUIRE, __HIP_MEMORY_SCOPE_WORKGROUP)

// ---------------- f32 -> f16 fragment-ordered conversion (proven R11) -------
__global__ __launch_bounds__(256) void conv_frag_kernel(const float* __restrict__ src,
                                                        unsigned* __restrict__ dst) {
    const unsigned t_lin = blockIdx.x * 256 + threadIdx.x;
    const unsigned chunk = t_lin >> 6, u = t_lin & 63;
    const unsigned l = ((u & 3) << 4) | (u >> 2);
    const unsigned t = (chunk << 6) | l;

    const int ll = t & 63;
    const int j  = (t >> 6) & 15;
    const int mt = (t >> 10) & 3;
    const int w  = (t >> 12) & 7;
    const int b  = (t >> 15) & 3;
    const int m  = (int)(t >> 17);
    const int kc = (4 * b + j) & 15;
    const int g  = ll >> 4, r16 = ll & 15;
    const int lr = w * 64 + mt * 16 + r16;
    const int gr = (lr >> 7) * 512 + b * 128 + (lr & 127);

    const float* sp = src + ((size_t)m * G4 + gr) * HID + kc * 32 + g * 8;
    const float4 a = *reinterpret_cast<const float4*>(sp);
    const float4 c = *reinterpret_cast<const float4*>(sp + 4);
    __half2 h0 = __floats2half2_rn(a.x, a.y);
    __half2 h1 = __floats2half2_rn(a.z, a.w);
    __half2 h2 = __floats2half2_rn(c.x, c.y);
    __half2 h3 = __floats2half2_rn(c.z, c.w);
    uint4 o;
    o.x = *reinterpret_cast<unsigned*>(&h0);
    o.y = *reinterpret_cast<unsigned*>(&h1);
    o.z = *reinterpret_cast<unsigned*>(&h2);
    o.w = *reinterpret_cast<unsigned*>(&h3);
    *reinterpret_cast<uint4*>(dst + (size_t)t * 4) = o;
}

// ---------------- MFMA LSTM, 1 barrier/step + per-region flags --------------
// 4 blocks/module, 512 thr (8 waves), 1 block/CU. Per step:
//   loop-top barrier (gates ready) -> ALL waves compute cell redundantly
//   (bit-identical; local h lands in wave-private h_loc[w], wave 0 stores hx)
//   -> local 4 MFMA chunks overlap remote RTT -> reader waves 2/3/4 each
//   poll ONE region (one poll per word; R12's redundancy mistake avoided),
//   stage h_rem[slot], release rflag[slot]=seq -> consumers acquire-spin per
//   slot and process that region's chunks (pipelined tail). Flags monotonic;
//   loop-top barrier protects h_rem/gates reuse across steps; acyclic ->
//   deadlock-free (grounded at t=0: gates(0) from prologue).
__global__
__attribute__((amdgpu_flat_work_group_size(512, 512), amdgpu_waves_per_eu(2, 2)))
void lstm_mfma_kernel(
    const float* __restrict__ recent,
    const float* __restrict__ history,
    const float* __restrict__ W_ih,
    const float* __restrict__ b_ih,
    const float* __restrict__ b_hh,
    const float* __restrict__ lin_W,
    const float* __restrict__ lin_b,
    const unsigned* __restrict__ wf,    // fragment-ordered f16 weights
    unsigned long long* hx,             // [2][64][256] seq-tagged pairs, zeroed
    float* __restrict__ per_mod)        // [64]
{
    const int bid = blockIdx.x;
    const int m = (bid & 7) * 8 + (bid >> 5);
    const int b = (bid >> 3) & 3;
    const int tid = threadIdx.x;
    const int w   = tid >> 6;   // wave 0..7
    const int l   = tid & 63;
    const int g   = l >> 4;     // 16-lane group 0..3
    const int c16 = l & 15;

    __shared__ uint4 w_lds[8][4][4][64];   // 128 KB [wave][mt][j2][lane]
    __shared__ unsigned h_loc[8][64];      // per-wave local h payloads
    __shared__ unsigned h_rem[192];        // staged remote h: [slot][64]
    __shared__ unsigned rflag[3];          // per-slot seq flags
    __shared__ float gates_sh[512];
    __shared__ float hist_sh[TSTEPS];
    __shared__ float red_sh[8];

    for (int i = tid; i < TSTEPS; i += 512)
        hist_sh[i] = history[(size_t)m * TSTEPS + i];
    if (tid < 3) rflag[tid] = 0;

    // ---- load fragment weights: 12 K-chunks/tile in regs, 4 in LDS ----
    const uint4* fb = (const uint4*)wf + (size_t)((m * 4 + b) * 8 + w) * 4096;
    uint4 wr[4][12];
    #pragma unroll
    for (int mt = 0; mt < 4; ++mt)
        #pragma unroll
        for (int j = 0; j < 12; ++j)
            wr[mt][j] = fb[(mt * 16 + j) * 64 + l];
    #pragma unroll
    for (int mt = 0; mt < 4; ++mt)
        #pragma unroll
        for (int j2 = 0; j2 < 4; ++j2)
            w_lds[w][mt][j2][l] = fb[(mt * 16 + 12 + j2) * 64 + l];

    // gate-writeback constants: lanes c16<4 own tile mt=c16, rows g*4+e
    float wib4[4], bias4[4];
    if (c16 < 4) {
        #pragma unroll
        for (int e = 0; e < 4; ++e) {
            const int lr = w * 64 + c16 * 16 + g * 4 + e;
            const int gr = (lr >> 7) * 512 + b * 128 + (lr & 127);
            wib4[e]  = W_ih[(size_t)m * G4 + gr];
            bias4[e] = b_ih[(size_t)m * G4 + gr] + b_hh[(size_t)m * G4 + gr];
        }
    }

    const bool is_rdr = (w >= 2 && w <= 4);
    const int  rslot  = w - 2;                              // 0..2 (readers)
    const int  rword  = (((b + 1 + rslot) & 3) << 6) + l;   // hx word to poll

    float c0 = 0.0f, c1 = 0.0f;   // cell state: lane l holds elems 2l, 2l+1
    __syncthreads();   // hist/rflag staged

    // prologue gates(t=0): h(0)=0 -> input+bias only
    if (c16 < 4) {
        const float x0 = hist_sh[0];
        float4 o;
        o.x = x0 * wib4[0] + bias4[0];
        o.y = x0 * wib4[1] + bias4[1];
        o.z = x0 * wib4[2] + bias4[2];
        o.w = x0 * wib4[3] + bias4[3];
        *reinterpret_cast<float4*>(&gates_sh[w * 64 + c16 * 16 + g * 4]) = o;
    }

    for (int t = 0; t < TSTEPS - 1; ++t) {
        __syncthreads();   // gates(t) ready -- the ONLY barrier per step
        const unsigned seq = (unsigned)(t + 1);
        const size_t pbase = (size_t)(seq & 1) * (NMOD * 256) + (size_t)m * 256;

        // ---- all-wave redundant cell (deterministic -> identical) ----
        {
            const int e0 = 2 * l, e1 = 2 * l + 1;
            const float gi0 = fsig(gates_sh[e0]);
            const float gf0 = fsig(gates_sh[128 + e0]);
            const float gg0 = ftanh_(gates_sh[256 + e0]);
            const float go0 = fsig(gates_sh[384 + e0]);
            c0 = gf0 * c0 + gi0 * gg0;
            const float h0 = go0 * ftanh_(c0);
            const float gi1 = fsig(gates_sh[e1]);
            const float gf1 = fsig(gates_sh[128 + e1]);
            const float gg1 = ftanh_(gates_sh[256 + e1]);
            const float go1 = fsig(gates_sh[384 + e1]);
            c1 = gf1 * c1 + gi1 * gg1;
            const float h1 = go1 * ftanh_(c1);
            __half2 hh = __floats2half2_rn(h0, h1);
            const unsigned pay = *reinterpret_cast<unsigned*>(&hh);
            if (w == 0)
                __hip_atomic_store(&hx[pbase + (b << 6) + l],
                                   ((unsigned long long)seq << 32) | pay,
                                   __ATOMIC_RELAXED, __HIP_MEMORY_SCOPE_AGENT);
            h_loc[w][l] = pay;   // wave-private: same-wave read, no barrier
        }

        unsigned long long pv = 0;
        if (is_rdr) pv = ALOAD(&hx[pbase + rword]);   // speculative poll

        f32x4_t acc0 = {0.f, 0.f, 0.f, 0.f};
        f32x4_t acc1 = {0.f, 0.f, 0.f, 0.f};
        f32x4_t acc2 = {0.f, 0.f, 0.f, 0.f};
        f32x4_t acc3 = {0.f, 0.f, 0.f, 0.f};

        // ---- local K-chunks (j=0..3) overlap remote RTT ----
        #pragma unroll
        for (int j = 0; j < 4; ++j) {
            const half8_t hv8 = h8(*(const uint4*)&h_loc[w][j * 16 + g * 4]);
            acc0 = MFMA_F16(h8(wr[0][j]), hv8, acc0);
            acc1 = MFMA_F16(h8(wr[1][j]), hv8, acc1);
            acc2 = MFMA_F16(h8(wr[2][j]), hv8, acc2);
            acc3 = MFMA_F16(h8(wr[3][j]), hv8, acc3);
        }

        // readers: finish poll, stage region, release its flag
        if (is_rdr) {
            while ((unsigned)(pv >> 32) != seq)
                pv = ALOAD(&hx[pbase + rword]);
            h_rem[rslot * 64 + l] = (unsigned)pv;
            if (l == 0) FLAG_SET(&rflag[rslot], seq);
        }

        // ---- remote regions, pipelined on per-slot flags ----
        #pragma unroll
        for (int s = 0; s < 2; ++s) {
            while (FLAG_GET(&rflag[s]) != seq) {}
            #pragma unroll
            for (int q = 0; q < 4; ++q) {
                const int j = 4 + s * 4 + q;
                const half8_t hv8 = h8(*(const uint4*)&h_rem[s * 64 + q * 16 + g * 4]);
                acc0 = MFMA_F16(h8(wr[0][j]), hv8, acc0);
                acc1 = MFMA_F16(h8(wr[1][j]), hv8, acc1);
                acc2 = MFMA_F16(h8(wr[2][j]), hv8, acc2);
                acc3 = MFMA_F16(h8(wr[3][j]), hv8, acc3);
            }
        }
        while (FLAG_GET(&rflag[2]) != seq) {}
        #pragma unroll
        for (int j2 = 0; j2 < 4; ++j2) {
            const half8_t hv8 = h8(*(const uint4*)&h_rem[2 * 64 + j2 * 16 + g * 4]);
            acc0 = MFMA_F16(h8(w_lds[w][0][j2][l]), hv8, acc0);
            acc1 = MFMA_F16(h8(w_lds[w][1][j2][l]), hv8, acc1);
            acc2 = MFMA_F16(h8(w_lds[w][2][j2][l]), hv8, acc2);
            acc3 = MFMA_F16(h8(w_lds[w][3][j2][l]), hv8, acc3);
        }

        // D cols identical (B bcast): lane (g, c16<4) holds rows g*4+e of
        // tile c16 -> direct float4 gate writeback.
        if (c16 < 4) {
            const f32x4_t a = (c16 == 0) ? acc0 : (c16 == 1) ? acc1
                             : (c16 == 2) ? acc2 : acc3;
            const float x1 = hist_sh[t + 1];
            float4 o;
            o.x = a[0] + x1 * wib4[0] + bias4[0];
            o.y = a[1] + x1 * wib4[1] + bias4[1];
            o.z = a[2] + x1 * wib4[2] + bias4[2];
            o.w = a[3] + x1 * wib4[3] + bias4[3];
            *reinterpret_cast<float4*>(&gates_sh[w * 64 + c16 * 16 + g * 4]) = o;
        }
    }

    // ---- epilogue: final cell (t = TSTEPS-1) + final exchange ----
    __syncthreads();   // gates(T-1) ready
    {
        const unsigned seq = (unsigned)TSTEPS;
        const size_t pbase = (size_t)(seq & 1) * (NMOD * 256) + (size_t)m * 256;
        {
            const int e0 = 2 * l, e1 = 2 * l + 1;
            const float gi0 = fsig(gates_sh[e0]);
            const float gf0 = fsig(gates_sh[128 + e0]);
            const float gg0 = ftanh_(gates_sh[256 + e0]);
            const float go0 = fsig(gates_sh[384 + e0]);
            c0 = gf0 * c0 + gi0 * gg0;
            const float h0 = go0 * ftanh_(c0);
            const float gi1 = fsig(gates_sh[e1]);
            const float gf1 = fsig(gates_sh[128 + e1]);
            const float gg1 = ftanh_(gates_sh[256 + e1]);
            const float go1 = fsig(gates_sh[384 + e1]);
            c1 = gf1 * c1 + gi1 * gg1;
            const float h1 = go1 * ftanh_(c1);
            __half2 hh = __floats2half2_rn(h0, h1);
            const unsigned pay = *reinterpret_cast<unsigned*>(&hh);
            if (w == 0)
                __hip_atomic_store(&hx[pbase + (b << 6) + l],
                                   ((unsigned long long)seq << 32) | pay,
                                   __ATOMIC_RELAXED, __HIP_MEMORY_SCOPE_AGENT);
        }
        if (b == 0) {
            __syncthreads();   // cell reads of gates_sh done before reuse
            unsigned* hfin = (unsigned*)gates_sh;
            if (tid < 256) {
                unsigned long long pv;
                do {
                    pv = ALOAD(&hx[pbase + tid]);
                } while ((unsigned)(pv >> 32) != seq);
                hfin[tid] = (unsigned)pv;
            }
            __syncthreads();
            // per-module linear from f16 h
            float v = 0.0f;
            if (tid < 256) {
                const __half2 u = *reinterpret_cast<const __half2*>(&hfin[tid]);
                const float* lwp = lin_W + (size_t)m * (HID + 1);
                v = __half2float(u.x) * lwp[2 * tid] + __half2float(u.y) * lwp[2 * tid + 1];
            }
            #pragma unroll
            for (int s2 = 32; s2; s2 >>= 1) v += __shfl_xor(v, s2, 64);
            if ((tid & 63) == 0) red_sh[tid >> 6] = v;
            __syncthreads();
            if (tid == 0) {
                float s = 0.0f;
                #pragma unroll
                for (int wv2 = 0; wv2 < 8; ++wv2) s += red_sh[wv2];
                s += recent[m] * lin_W[(size_t)m * (HID + 1) + HID] + lin_b[m];
                per_mod[m] = s;
            }
        }
    }
}

// ---------------- fallback: round-1 f32 single-block-per-module kernel -------
__global__ __launch_bounds__(1024) void lstm_module_kernel(
    const float* __restrict__ recent,
    const float* __restrict__ history,
    const float* __restrict__ W_ih,
    const float* __restrict__ W_hh,
    const float* __restrict__ b_ih,
    const float* __restrict__ b_hh,
    const float* __restrict__ lin_W,
    const float* __restrict__ lin_b,
    float* __restrict__ per_mod)
{
    const int n = blockIdx.x;
    const int tid = threadIdx.x;

    __shared__ float h_sh[HID];
    __shared__ float gates_sh[G4];
    __shared__ float wib_sh[G4];
    __shared__ float bias_sh[G4];
    __shared__ float hist_sh[TSTEPS];

    for (int i = tid; i < G4; i += 1024) {
        wib_sh[i]  = W_ih[(size_t)n * G4 + i];
        bias_sh[i] = b_ih[(size_t)n * G4 + i] + b_hh[(size_t)n * G4 + i];
    }
    for (int i = tid; i < TSTEPS; i += 1024) hist_sh[i] = history[(size_t)n * TSTEPS + i];
    if (tid < HID) h_sh[tid] = 0.0f;
    float c_reg = 0.0f;
    __syncthreads();

    const int sub = tid & 15;
    const int rid = tid >> 4;
    const float* Wbase = W_hh + (size_t)n * G4 * HID;

    for (int t = 0; t < TSTEPS; ++t) {
        const float x = hist_sh[t];
        float hreg[32];
        #pragma unroll
        for (int j = 0; j < 8; ++j) {
            const float4 hv = *reinterpret_cast<const float4*>(&h_sh[sub * 4 + j * 64]);
            hreg[4 * j + 0] = hv.x; hreg[4 * j + 1] = hv.y;
            hreg[4 * j + 2] = hv.z; hreg[4 * j + 3] = hv.w;
        }
        for (int p = 0; p < 32; ++p) {
            const int r = p * 64 + rid;
            const float* wrp = Wbase + (size_t)r * HID + sub * 4;
            float acc = 0.0f;
            #pragma unroll
            for (int j = 0; j < 8; ++j) {
                const float4 wv = *reinterpret_cast<const float4*>(wrp + j * 64);
                acc += wv.x * hreg[4*j+0] + wv.y * hreg[4*j+1]
                     + wv.z * hreg[4*j+2] + wv.w * hreg[4*j+3];
            }
            acc += __shfl_xor(acc, 1, 64);
            acc += __shfl_xor(acc, 2, 64);
            acc += __shfl_xor(acc, 4, 64);
            acc += __shfl_xor(acc, 8, 64);
            if (sub == 0) gates_sh[r] = acc + x * wib_sh[r] + bias_sh[r];
        }
        __syncthreads();
        if (tid < HID) {
            const float ig = fsig(gates_sh[tid]);
            const float fg = fsig(gates_sh[HID + tid]);
            const float gg = ftanh_(gates_sh[2 * HID + tid]);
            const float og = fsig(gates_sh[3 * HID + tid]);
            c_reg = fg * c_reg + ig * gg;
            h_sh[tid] = og * ftanh_(c_reg);
        }
        __syncthreads();
    }

    if (tid < HID) {
        float v = h_sh[tid] * lin_W[(size_t)n * (HID + 1) + tid];
        #pragma unroll
        for (int m2 = 32; m2; m2 >>= 1) v += __shfl_xor(v, m2, 64);
        if ((tid & 63) == 0) gates_sh[tid >> 6] = v;
    }
    __syncthreads();
    if (tid == 0) {
        float s = 0.0f;
        #pragma unroll
        for (int w = 0; w < HID / 64; ++w) s += gates_sh[w];
        s += recent[n] * lin_W[(size_t)n * (HID + 1) + HID] + lin_b[n];
        per_mod[n] = s;
    }
}

__global__ void finish_kernel(const float* __restrict__ per_mod,
                              const float* __restrict__ final_W,
                              const float* __restrict__ final_b,
                              float* __restrict__ out)
{
    const int l = threadIdx.x;
    float v = per_mod[l] * final_W[l];
    #pragma unroll
    for (int m = 32; m; m >>= 1) v += __shfl_xor(v, m, 64);
    if (l == 0) out[0] = v + final_b[0];
}

extern "C" void kernel_launch(void* const* d_in, const int* in_sizes, int n_in,
                              void* d_out, int out_size, void* d_ws, size_t ws_size,
                              hipStream_t stream) {
    const float* recent  = (const float*)d_in[0];
    const float* history = (const float*)d_in[1];
    const float* W_ih    = (const float*)d_in[2];
    const float* W_hh    = (const float*)d_in[3];
    const float* b_ih    = (const float*)d_in[4];
    const float* b_hh    = (const float*)d_in[5];
    const float* lin_W   = (const float*)d_in[6];
    const float* lin_b   = (const float*)d_in[7];
    const float* final_W = (const float*)d_in[8];
    const float* final_b = (const float*)d_in[9];
    float* out = (float*)d_out;
    float* per_mod = (float*)d_ws;

    if (ws_size >= WS_NEED) {
        unsigned* wfrag = (unsigned*)((char*)d_ws + WOFF_W16);
        unsigned long long* hx = (unsigned long long*)((char*)d_ws + WOFF_HX);

        // zero per_mod + hx each call (ws is not re-poisoned between replays)
        hipMemsetAsync(d_ws, 0, WOFF_W16, stream);

        // 8.39M fragment entries, 1 per thread
        conv_frag_kernel<<<32768, 256, 0, stream>>>(W_hh, wfrag);

        lstm_mfma_kernel<<<NMOD * 4, 512, 0, stream>>>(
            recent, history, W_ih, b_ih, b_hh, lin_W, lin_b,
            wfrag, hx, per_mod);
    } else {
        lstm_module_kernel<<<NMOD, 1024, 0, stream>>>(
            recent, history, W_ih, W_hh, b_ih, b_hh, lin_W, lin_b, per_mod);
    }
    finish_kernel<<<1, 64, 0, stream>>>(per_mod, final_W, final_b, out);
}